// Round 1
// baseline (133.068 us; speedup 1.0000x reference)
//
#include <hip/hip_runtime.h>
#include <math.h>

// Problem constants (from reference setup_inputs)
#define NQ 2048
#define NB 8192
#define DIM 32

#define LOG2E 1.44269504088896340736f

typedef _Float16 half8 __attribute__((ext_vector_type(8)));
typedef float    f32x4 __attribute__((ext_vector_type(4)));

// ---------------- workspace layout (bytes, 64-B aligned) ----------------
#define WS_ACC 0         // 2*NQ f32 (16384 B)
#define WS_Q2  16448     // NQ f32
#define WS_B2  24640     // NB f32
#define WS_XQH 57408     // NQ*DIM f16   (A operand: xq*w rounded)
#define WS_XBH 188480    // NB*DIM f16   (B operand: -2*(xb*w) rounded-then-scaled)

// Pre: convert rows to f16 with norms computed FROM THE ROUNDED VALUES
// (so mfma d2 = ||a-b||^2 has no representation-mismatch cancellation).
// XBh is stored pre-scaled by -2 (exact: exponent+1 + sign) so the main
// MFMA with C = q2+b2 emits d2 directly.
__global__ __launch_bounds__(256) void relnw_pre(
    const float* __restrict__ xq, const float* __restrict__ xb,
    const float* __restrict__ w,
    _Float16* __restrict__ XQh, _Float16* __restrict__ XBh,
    float* __restrict__ q2, float* __restrict__ b2,
    float* __restrict__ acc)
{
    const int tid = threadIdx.x;
    const int gi  = blockIdx.x * 256 + tid;
    if (gi < 2 * NQ) acc[gi] = 0.f;      // zero atomic accumulators

    const int row = blockIdx.x * 64 + (tid >> 2);
    const int p   = tid & 3;             // 8-elem chunk within the row
    if (row >= NQ + NB) return;

    const float* src; _Float16* dst; float* s2; float scale;
    if (row < NQ) { src = xq + (size_t)row * DIM;
                    dst = XQh + (size_t)row * DIM; s2 = q2 + row; scale = 1.f; }
    else          { int j = row - NQ;
                    src = xb + (size_t)j * DIM;
                    dst = XBh + (size_t)j * DIM;   s2 = b2 + j;   scale = -2.f; }

    const float4 xa  = ((const float4*)src)[p * 2];
    const float4 xbv = ((const float4*)src)[p * 2 + 1];
    const float4 wa  = ((const float4*)w)[p * 2];
    const float4 wb  = ((const float4*)w)[p * 2 + 1];
    const float xs[8]  = {xa.x, xa.y, xa.z, xa.w, xbv.x, xbv.y, xbv.z, xbv.w};
    const float ws_[8] = {wa.x, wa.y, wa.z, wa.w, wb.x, wb.y, wb.z, wb.w};

    half8 h;
    float s = 0.f;
#pragma unroll
    for (int c = 0; c < 8; ++c) {
        float t = xs[c] * ws_[c];
        _Float16 hh = (_Float16)t;       // the rounding
        float th = (float)hh;
        s = fmaf(th, th, s);             // norm of the ROUNDED vector
        h[c] = (_Float16)(th * scale);   // exact scaling
    }
    *(half8*)(dst + p * 8) = h;          // coalesced 16-B store

    // row-norm: reduce over the 4 chunk-lanes (low 2 lane bits)
    s += __shfl_xor(s, 1, 64);
    s += __shfl_xor(s, 2, 64);
    if (p == 0) *s2 = s;
}

// Main: grid (8, 128) = 1024 blocks (4/CU), 256 threads (4 waves).
// Wave task: one 16-query tile x 256-bg chunk = 16 MFMA tiles.
// v_mfma_f32_16x16x32_f16 with A = xq*w (f16), B = -2*(xb*w) (f16),
// C[g] = q2+b2  ==>  D = d2 directly.
// C/D layout: col = lane&15 (bg), row = (lane>>4)*4 + reg (query).
//
// R7: R6's prefetch was defeated by vmcnt's in-order retirement — bfrag/yv/b2v
// were loaded AT USE, after the 16-deep rr batch, so consuming them forced
// vmcnt waits that drained the whole prefetch queue + exposed L2 latency
// every iteration. Also rr[2][RB][4] indexed by (bt&1) risked scratch (rule:
// runtime-indexed ext arrays spill). Fix: fully hand-unrolled pipeline,
// NAMED double buffers rrA/rrB (compile-time indices only), and bfrag/yv/b2v
// pipelined ONE iteration ahead via parity-alternating named registers
// (bfX/bfY etc). No use ever waits on a load issued after it.
//
// R5 lesson (keep): no __threadfence / fused finalize — a per-block agent-
// scope fence emits buffer_wbl2/inv and thrashes L2 for in-flight blocks.
#define BT_PER_WAVE 16
#define BG_PER_WAVE (BT_PER_WAVE * 16)   // 256
#define RB 4                             // r-prefetch batch (iterations)

// batch prefetch of r: 16 loads, all base + compile-time imm offset (<= 960 B)
#define PREF(RR, BT)                                                        \
  { _Pragma("unroll") for (int i_ = 0; i_ < RB; ++i_)                       \
    _Pragma("unroll") for (int g_ = 0; g_ < 4; ++g_)                        \
      RR[i_][g_] = rbase[g_][((BT) * RB + i_) * 16]; }

// per-iteration operands for iteration IT (issued one iteration early)
#define LOADOPS(IT, BF, YV, B2V)                                            \
  { BF  = *(const half8*)(xbp + (size_t)(IT) * 16 * DIM);                   \
    YV  = ybp[(IT) * 16];                                                   \
    B2V = b2p[(IT) * 16]; }

// compute one 16x16 tile from fully-resident registers
#define COMP(RR4, BF, YV, B2V)                                              \
  { f32x4 cin;                                                              \
    _Pragma("unroll") for (int g_ = 0; g_ < 4; ++g_)                        \
      cin[g_] = q2r[g_] + (B2V);                                            \
    f32x4 d2v = __builtin_amdgcn_mfma_f32_16x16x32_f16(                     \
        afrag, BF, cin, 0, 0, 0);                                           \
    _Pragma("unroll") for (int g_ = 0; g_ < 4; ++g_) {                      \
      float d2   = fmaxf(d2v[g_], 0.f);                                     \
      float dist = __builtin_amdgcn_sqrtf(d2);                              \
      float e    = fmaf(dist, c1, (RR4)[g_] * c2);                          \
      float k    = __builtin_amdgcn_exp2f(e);                               \
      sk[g_] += k;                                                          \
      sky[g_] = fmaf(k, (YV), sky[g_]); } }

__global__ __launch_bounds__(256, 4) void relnw_main(
    const _Float16* __restrict__ XQh,  // (NQ, DIM)
    const _Float16* __restrict__ XBh,  // (NB, DIM), pre-scaled by -2
    const float* __restrict__ q2,      // (NQ,)
    const float* __restrict__ b2,      // (NB,)
    const float* __restrict__ yb,      // (NB,)
    const float* __restrict__ r,       // (NQ, NB)
    const float* __restrict__ sigma,   // (1,)
    const float* __restrict__ rscale,  // (1,)
    float* __restrict__ acc)           // [0:NQ]=sum_k, [NQ:2NQ]=sum_k*y
{
    const int tid  = threadIdx.x;
    const int lane = tid & 63;
    const int wid  = tid >> 6;
    const int m    = lane & 15;   // A row (query) / B col (bg) / C col (bg)
    const int quad = lane >> 4;   // 0..3

    const int q0     = blockIdx.y * 16;
    const int bstart = (blockIdx.x * 4 + wid) * BG_PER_WAVE;

    const float c1 = -LOG2E / sigma[0];   // coeff on dist (log2 space)
    const float c2 =  LOG2E * rscale[0];  // coeff on r

    // A fragment for this wave's 16 queries (fixed across the b-loop)
    const half8 afrag = *(const half8*)(XQh + (size_t)(q0 + m) * DIM + quad * 8);

    float q2r[4];
#pragma unroll
    for (int g = 0; g < 4; ++g) q2r[g] = q2[q0 + quad * 4 + g];

    const _Float16* xbp = XBh + (size_t)(bstart + m) * DIM + quad * 8;
    const float*    ybp = yb + bstart + m;
    const float*    b2p = b2 + bstart + m;

    // 4 r row-base pointers; every r load below is base + compile-time offset
    const float* rbase[4];
#pragma unroll
    for (int g = 0; g < 4; ++g)
        rbase[g] = r + (size_t)(q0 + quad * 4 + g) * NB + bstart + m;

    float sk[4]  = {0.f, 0.f, 0.f, 0.f};
    float sky[4] = {0.f, 0.f, 0.f, 0.f};

    // named double buffers — every index below is a compile-time constant
    float rrA[RB][4], rrB[RB][4];
    half8 bfX, bfY;
    float yvX, yvY, b2X, b2Y;

    // ---- prologue: iter-0 operands first (oldest -> retire first), then
    //      two full r batches (32 loads in flight) ----
    LOADOPS(0, bfX, yvX, b2X)
    PREF(rrA, 0)
    PREF(rrB, 1)

    // ---- steady state: issue ops for it+1, compute it from registers.
    //      r batch for n+2 issued right after batch n is consumed. ----
    LOADOPS(1,  bfY, yvY, b2Y)  COMP(rrA[0], bfX, yvX, b2X)
    LOADOPS(2,  bfX, yvX, b2X)  COMP(rrA[1], bfY, yvY, b2Y)
    LOADOPS(3,  bfY, yvY, b2Y)  COMP(rrA[2], bfX, yvX, b2X)
    LOADOPS(4,  bfX, yvX, b2X)  COMP(rrA[3], bfY, yvY, b2Y)
    PREF(rrA, 2)
    LOADOPS(5,  bfY, yvY, b2Y)  COMP(rrB[0], bfX, yvX, b2X)
    LOADOPS(6,  bfX, yvX, b2X)  COMP(rrB[1], bfY, yvY, b2Y)
    LOADOPS(7,  bfY, yvY, b2Y)  COMP(rrB[2], bfX, yvX, b2X)
    LOADOPS(8,  bfX, yvX, b2X)  COMP(rrB[3], bfY, yvY, b2Y)
    PREF(rrB, 3)
    LOADOPS(9,  bfY, yvY, b2Y)  COMP(rrA[0], bfX, yvX, b2X)
    LOADOPS(10, bfX, yvX, b2X)  COMP(rrA[1], bfY, yvY, b2Y)
    LOADOPS(11, bfY, yvY, b2Y)  COMP(rrA[2], bfX, yvX, b2X)
    LOADOPS(12, bfX, yvX, b2X)  COMP(rrA[3], bfY, yvY, b2Y)
    LOADOPS(13, bfY, yvY, b2Y)  COMP(rrB[0], bfX, yvX, b2X)
    LOADOPS(14, bfX, yvX, b2X)  COMP(rrB[1], bfY, yvY, b2Y)
    LOADOPS(15, bfY, yvY, b2Y)  COMP(rrB[2], bfX, yvX, b2X)
                                COMP(rrB[3], bfY, yvY, b2Y)

    // Reduce across the 16 bg-columns (low 4 lane bits), once per wave.
#pragma unroll
    for (int off = 1; off <= 8; off <<= 1) {
#pragma unroll
        for (int g = 0; g < 4; ++g) {
            sk[g]  += __shfl_xor(sk[g],  off, 64);
            sky[g] += __shfl_xor(sky[g], off, 64);
        }
    }
    if (m == 0) {
#pragma unroll
        for (int g = 0; g < 4; ++g) {
            atomicAdd(acc + (q0 + quad * 4 + g),      sk[g]);
            atomicAdd(acc + NQ + (q0 + quad * 4 + g), sky[g]);
        }
    }
}

__global__ __launch_bounds__(256) void relnw_finalize(
    const float* __restrict__ acc, float* __restrict__ out)
{
    int q = blockIdx.x * 256 + threadIdx.x;
    if (q < NQ)
        out[q] = acc[NQ + q] / (acc[q] + 1e-8f);
}

extern "C" void kernel_launch(void* const* d_in, const int* in_sizes, int n_in,
                              void* d_out, int out_size, void* d_ws, size_t ws_size,
                              hipStream_t stream) {
    const float* xb     = (const float*)d_in[0]; // (8192,32)
    const float* yb     = (const float*)d_in[1]; // (8192,)
    const float* xq     = (const float*)d_in[2]; // (2048,32)
    const float* r      = (const float*)d_in[3]; // (2048,8192)
    const float* sigma  = (const float*)d_in[4]; // (1,)
    const float* rscale = (const float*)d_in[5]; // (1,)
    const float* w      = (const float*)d_in[6]; // (32,)
    float* out = (float*)d_out;

    char* ws = (char*)d_ws;
    float*    acc = (float*)(ws + WS_ACC);
    float*    q2  = (float*)(ws + WS_Q2);
    float*    b2  = (float*)(ws + WS_B2);
    _Float16* XQh = (_Float16*)(ws + WS_XQH);
    _Float16* XBh = (_Float16*)(ws + WS_XBH);

    relnw_pre<<<(NQ + NB) / 64, 256, 0, stream>>>(xq, xb, w, XQh, XBh, q2, b2, acc);

    dim3 grid(NB / (4 * BG_PER_WAVE), NQ / 16);  // (8, 128) = 1024 blocks
    relnw_main<<<grid, 256, 0, stream>>>(XQh, XBh, q2, b2, yb, r, sigma, rscale, acc);

    relnw_finalize<<<(NQ + 255) / 256, 256, 0, stream>>>(acc, out);
}

// Round 2
// 113.980 us; speedup vs baseline: 1.1675x; 1.1675x over previous
//
#include <hip/hip_runtime.h>
#include <math.h>

// Problem constants (from reference setup_inputs)
#define NQ 2048
#define NB 8192
#define DIM 32

#define LOG2E 1.44269504088896340736f

typedef _Float16 half8 __attribute__((ext_vector_type(8)));
typedef float    f32x4 __attribute__((ext_vector_type(4)));

// ---------------- workspace layout (bytes, 64-B aligned) ----------------
#define WS_ACC 0         // 2*NQ f32 (16384 B)
#define WS_Q2  16448     // NQ f32
#define WS_B2  24640     // NB f32
#define WS_XQH 57408     // NQ*DIM f16   (A operand: xq*w rounded)
#define WS_XBH 188480    // NB*DIM f16   (B operand: -2*(xb*w) rounded-then-scaled)

// Pre: convert rows to f16 with norms computed FROM THE ROUNDED VALUES
// (so mfma d2 = ||a-b||^2 has no representation-mismatch cancellation).
// XBh is stored pre-scaled by -2 (exact: exponent+1 + sign) so the main
// MFMA with C = q2+b2 emits d2 directly.
__global__ __launch_bounds__(256) void relnw_pre(
    const float* __restrict__ xq, const float* __restrict__ xb,
    const float* __restrict__ w,
    _Float16* __restrict__ XQh, _Float16* __restrict__ XBh,
    float* __restrict__ q2, float* __restrict__ b2,
    float* __restrict__ acc)
{
    const int tid = threadIdx.x;
    const int gi  = blockIdx.x * 256 + tid;
    if (gi < 2 * NQ) acc[gi] = 0.f;      // zero atomic accumulators

    const int row = blockIdx.x * 64 + (tid >> 2);
    const int p   = tid & 3;             // 8-elem chunk within the row
    if (row >= NQ + NB) return;

    const float* src; _Float16* dst; float* s2; float scale;
    if (row < NQ) { src = xq + (size_t)row * DIM;
                    dst = XQh + (size_t)row * DIM; s2 = q2 + row; scale = 1.f; }
    else          { int j = row - NQ;
                    src = xb + (size_t)j * DIM;
                    dst = XBh + (size_t)j * DIM;   s2 = b2 + j;   scale = -2.f; }

    const float4 xa  = ((const float4*)src)[p * 2];
    const float4 xbv = ((const float4*)src)[p * 2 + 1];
    const float4 wa  = ((const float4*)w)[p * 2];
    const float4 wb  = ((const float4*)w)[p * 2 + 1];
    const float xs[8]  = {xa.x, xa.y, xa.z, xa.w, xbv.x, xbv.y, xbv.z, xbv.w};
    const float ws_[8] = {wa.x, wa.y, wa.z, wa.w, wb.x, wb.y, wb.z, wb.w};

    half8 h;
    float s = 0.f;
#pragma unroll
    for (int c = 0; c < 8; ++c) {
        float t = xs[c] * ws_[c];
        _Float16 hh = (_Float16)t;       // the rounding
        float th = (float)hh;
        s = fmaf(th, th, s);             // norm of the ROUNDED vector
        h[c] = (_Float16)(th * scale);   // exact scaling
    }
    *(half8*)(dst + p * 8) = h;          // coalesced 16-B store

    // row-norm: reduce over the 4 chunk-lanes (low 2 lane bits)
    s += __shfl_xor(s, 1, 64);
    s += __shfl_xor(s, 2, 64);
    if (p == 0) *s2 = s;
}

// Main: grid (8, 128) = 1024 blocks (4/CU), 256 threads (4 waves).
// Wave task: one 16-query tile x 256-bg chunk = 16 MFMA tiles.
// v_mfma_f32_16x16x32_f16 with A = xq*w (f16), B = -2*(xb*w) (f16),
// C[g] = q2+b2  ==>  D = d2 directly.
// C/D layout: col = lane&15 (bg), row = (lane>>4)*4 + reg (query).
//
// R7 (structure, keep): fully hand-unrolled pipeline, NAMED double buffers
// rrA/rrB (compile-time indices only), bfrag/yv/b2v pipelined one iteration
// ahead via parity-alternating named regs. In-order vmcnt retirement means
// waiting on an older load never drains younger prefetches.
//
// R8 (fix): R7 used __launch_bounds__(256,4) -> compiler capped VGPRs at
// 64 (=256/4 budget model) -> the whole pipeline spilled to scratch
// (VGPR_Count=64, WRITE_SIZE=37 MB of spill traffic, main 42.4us).
// (256,2) caps at 128; the kernel needs ~100-110 live VGPRs, which still
// gives 4 waves/SIMD hardware occupancy (tier boundary is 128).
//
// R5 lesson (keep): no __threadfence / fused finalize — a per-block agent-
// scope fence emits buffer_wbl2/inv and thrashes L2 for in-flight blocks.
#define BT_PER_WAVE 16
#define BG_PER_WAVE (BT_PER_WAVE * 16)   // 256
#define RB 4                             // r-prefetch batch (iterations)

// batch prefetch of r: 16 loads, all base + compile-time imm offset (<= 960 B)
#define PREF(RR, BT)                                                        \
  { _Pragma("unroll") for (int i_ = 0; i_ < RB; ++i_)                       \
    _Pragma("unroll") for (int g_ = 0; g_ < 4; ++g_)                        \
      RR[i_][g_] = rbase[g_][((BT) * RB + i_) * 16]; }

// per-iteration operands for iteration IT (issued one iteration early)
#define LOADOPS(IT, BF, YV, B2V)                                            \
  { BF  = *(const half8*)(xbp + (size_t)(IT) * 16 * DIM);                   \
    YV  = ybp[(IT) * 16];                                                   \
    B2V = b2p[(IT) * 16]; }

// compute one 16x16 tile from fully-resident registers
#define COMP(RR4, BF, YV, B2V)                                              \
  { f32x4 cin;                                                              \
    _Pragma("unroll") for (int g_ = 0; g_ < 4; ++g_)                        \
      cin[g_] = q2r[g_] + (B2V);                                            \
    f32x4 d2v = __builtin_amdgcn_mfma_f32_16x16x32_f16(                     \
        afrag, BF, cin, 0, 0, 0);                                           \
    _Pragma("unroll") for (int g_ = 0; g_ < 4; ++g_) {                      \
      float d2   = fmaxf(d2v[g_], 0.f);                                     \
      float dist = __builtin_amdgcn_sqrtf(d2);                              \
      float e    = fmaf(dist, c1, (RR4)[g_] * c2);                          \
      float k    = __builtin_amdgcn_exp2f(e);                               \
      sk[g_] += k;                                                          \
      sky[g_] = fmaf(k, (YV), sky[g_]); } }

__global__ __launch_bounds__(256, 2) void relnw_main(
    const _Float16* __restrict__ XQh,  // (NQ, DIM)
    const _Float16* __restrict__ XBh,  // (NB, DIM), pre-scaled by -2
    const float* __restrict__ q2,      // (NQ,)
    const float* __restrict__ b2,      // (NB,)
    const float* __restrict__ yb,      // (NB,)
    const float* __restrict__ r,       // (NQ, NB)
    const float* __restrict__ sigma,   // (1,)
    const float* __restrict__ rscale,  // (1,)
    float* __restrict__ acc)           // [0:NQ]=sum_k, [NQ:2NQ]=sum_k*y
{
    const int tid  = threadIdx.x;
    const int lane = tid & 63;
    const int wid  = tid >> 6;
    const int m    = lane & 15;   // A row (query) / B col (bg) / C col (bg)
    const int quad = lane >> 4;   // 0..3

    const int q0     = blockIdx.y * 16;
    const int bstart = (blockIdx.x * 4 + wid) * BG_PER_WAVE;

    const float c1 = -LOG2E / sigma[0];   // coeff on dist (log2 space)
    const float c2 =  LOG2E * rscale[0];  // coeff on r

    // A fragment for this wave's 16 queries (fixed across the b-loop)
    const half8 afrag = *(const half8*)(XQh + (size_t)(q0 + m) * DIM + quad * 8);

    float q2r[4];
#pragma unroll
    for (int g = 0; g < 4; ++g) q2r[g] = q2[q0 + quad * 4 + g];

    const _Float16* xbp = XBh + (size_t)(bstart + m) * DIM + quad * 8;
    const float*    ybp = yb + bstart + m;
    const float*    b2p = b2 + bstart + m;

    // 4 r row-base pointers; every r load below is base + compile-time offset
    const float* rbase[4];
#pragma unroll
    for (int g = 0; g < 4; ++g)
        rbase[g] = r + (size_t)(q0 + quad * 4 + g) * NB + bstart + m;

    float sk[4]  = {0.f, 0.f, 0.f, 0.f};
    float sky[4] = {0.f, 0.f, 0.f, 0.f};

    // named double buffers — every index below is a compile-time constant
    float rrA[RB][4], rrB[RB][4];
    half8 bfX, bfY;
    float yvX, yvY, b2X, b2Y;

    // ---- prologue: iter-0 operands first (oldest -> retire first), then
    //      two full r batches (32 loads in flight) ----
    LOADOPS(0, bfX, yvX, b2X)
    PREF(rrA, 0)
    PREF(rrB, 1)

    // ---- steady state: issue ops for it+1, compute it from registers.
    //      r batch for n+2 issued right after batch n is consumed. ----
    LOADOPS(1,  bfY, yvY, b2Y)  COMP(rrA[0], bfX, yvX, b2X)
    LOADOPS(2,  bfX, yvX, b2X)  COMP(rrA[1], bfY, yvY, b2Y)
    LOADOPS(3,  bfY, yvY, b2Y)  COMP(rrA[2], bfX, yvX, b2X)
    LOADOPS(4,  bfX, yvX, b2X)  COMP(rrA[3], bfY, yvY, b2Y)
    PREF(rrA, 2)
    LOADOPS(5,  bfY, yvY, b2Y)  COMP(rrB[0], bfX, yvX, b2X)
    LOADOPS(6,  bfX, yvX, b2X)  COMP(rrB[1], bfY, yvY, b2Y)
    LOADOPS(7,  bfY, yvY, b2Y)  COMP(rrB[2], bfX, yvX, b2X)
    LOADOPS(8,  bfX, yvX, b2X)  COMP(rrB[3], bfY, yvY, b2Y)
    PREF(rrB, 3)
    LOADOPS(9,  bfY, yvY, b2Y)  COMP(rrA[0], bfX, yvX, b2X)
    LOADOPS(10, bfX, yvX, b2X)  COMP(rrA[1], bfY, yvY, b2Y)
    LOADOPS(11, bfY, yvY, b2Y)  COMP(rrA[2], bfX, yvX, b2X)
    LOADOPS(12, bfX, yvX, b2X)  COMP(rrA[3], bfY, yvY, b2Y)
    LOADOPS(13, bfY, yvY, b2Y)  COMP(rrB[0], bfX, yvX, b2X)
    LOADOPS(14, bfX, yvX, b2X)  COMP(rrB[1], bfY, yvY, b2Y)
    LOADOPS(15, bfY, yvY, b2Y)  COMP(rrB[2], bfX, yvX, b2X)
                                COMP(rrB[3], bfY, yvY, b2Y)

    // Reduce across the 16 bg-columns (low 4 lane bits), once per wave.
#pragma unroll
    for (int off = 1; off <= 8; off <<= 1) {
#pragma unroll
        for (int g = 0; g < 4; ++g) {
            sk[g]  += __shfl_xor(sk[g],  off, 64);
            sky[g] += __shfl_xor(sky[g], off, 64);
        }
    }
    if (m == 0) {
#pragma unroll
        for (int g = 0; g < 4; ++g) {
            atomicAdd(acc + (q0 + quad * 4 + g),      sk[g]);
            atomicAdd(acc + NQ + (q0 + quad * 4 + g), sky[g]);
        }
    }
}

__global__ __launch_bounds__(256) void relnw_finalize(
    const float* __restrict__ acc, float* __restrict__ out)
{
    int q = blockIdx.x * 256 + threadIdx.x;
    if (q < NQ)
        out[q] = acc[NQ + q] / (acc[q] + 1e-8f);
}

extern "C" void kernel_launch(void* const* d_in, const int* in_sizes, int n_in,
                              void* d_out, int out_size, void* d_ws, size_t ws_size,
                              hipStream_t stream) {
    const float* xb     = (const float*)d_in[0]; // (8192,32)
    const float* yb     = (const float*)d_in[1]; // (8192,)
    const float* xq     = (const float*)d_in[2]; // (2048,32)
    const float* r      = (const float*)d_in[3]; // (2048,8192)
    const float* sigma  = (const float*)d_in[4]; // (1,)
    const float* rscale = (const float*)d_in[5]; // (1,)
    const float* w      = (const float*)d_in[6]; // (32,)
    float* out = (float*)d_out;

    char* ws = (char*)d_ws;
    float*    acc = (float*)(ws + WS_ACC);
    float*    q2  = (float*)(ws + WS_Q2);
    float*    b2  = (float*)(ws + WS_B2);
    _Float16* XQh = (_Float16*)(ws + WS_XQH);
    _Float16* XBh = (_Float16*)(ws + WS_XBH);

    relnw_pre<<<(NQ + NB) / 64, 256, 0, stream>>>(xq, xb, w, XQh, XBh, q2, b2, acc);

    dim3 grid(NB / (4 * BG_PER_WAVE), NQ / 16);  // (8, 128) = 1024 blocks
    relnw_main<<<grid, 256, 0, stream>>>(XQh, XBh, q2, b2, yb, r, sigma, rscale, acc);

    relnw_finalize<<<(NQ + 255) / 256, 256, 0, stream>>>(acc, out);
}